// Round 1
// baseline (5683.314 us; speedup 1.0000x reference)
//
#include <hip/hip_runtime.h>
#include <hip/hip_bf16.h>

#define BATCH 128
#define SEQ   80
#define EMB   100
#define UNITS 2048
#define EPAD  128   // K-pad for the embedding matmul (100 -> 128)

typedef __attribute__((ext_vector_type(8))) short bf16x8;
typedef __attribute__((ext_vector_type(4))) float f32x4;

static __device__ __forceinline__ short f2bf(float f) {
  __hip_bfloat16 h = __float2bfloat16(f);
  return *reinterpret_cast<short*>(&h);
}

// ---------------------------------------------------------------------------
// Pack a row-major fp32 [K][N] weight matrix into MFMA B-operand layout:
// dst[c][kk][lane][j] = bf16(src[kk*32 + (lane>>4)*8 + j][c*16 + (lane&15)])
// One 64-lane wave handles one (c,kk) unit; 4 units per 256-thread block.
// Rows k >= Ksrc are zero (K padding for W0).
// ---------------------------------------------------------------------------
__global__ __launch_bounds__(256) void pack_b_kernel(
    const float* __restrict__ src, int Ksrc, int N, int nch, int totalUnits,
    short* __restrict__ dst) {
  int lane = threadIdx.x & 63;
  int u = blockIdx.x * 4 + (threadIdx.x >> 6);
  if (u >= totalUnits) return;
  int c  = u / nch;
  int kk = u - c * nch;
  int n  = c * 16 + (lane & 15);
  int k0 = kk * 32 + ((lane >> 4) << 3);
  bf16x8 v;
#pragma unroll
  for (int j = 0; j < 8; ++j) {
    int k = k0 + j;
    float f = (k < Ksrc) ? src[k * N + n] : 0.f;
    v[j] = f2bf(f);
  }
  *reinterpret_cast<bf16x8*>(dst + (u * 64 + lane) * 8) = v;
}

// ---------------------------------------------------------------------------
// Gather + K-pad embeddings: E[t][b][k] = bf16(emb[tokens[b][t]][k]) (k<100),
// zero for 100 <= k < 128. Row-major [SEQ][BATCH][EPAD].
// ---------------------------------------------------------------------------
__global__ __launch_bounds__(256) void pack_e_kernel(
    const int* __restrict__ tokens, const float* __restrict__ emb,
    __hip_bfloat16* __restrict__ E) {
  int idx = blockIdx.x * 256 + threadIdx.x;
  if (idx >= SEQ * BATCH * EPAD) return;
  int k  = idx & (EPAD - 1);
  int bt = idx >> 7;          // t*BATCH + b
  int b  = bt & (BATCH - 1);
  int t  = bt >> 7;
  int tok = tokens[b * SEQ + t];
  float f = (k < EMB) ? emb[tok * EMB + k] : 0.f;
  E[idx] = __float2bfloat16(f);
}

// ---------------------------------------------------------------------------
// One RNN stage: H = tanh(A1 @ B1 + A2 @ B2 + bias)
//   A1: [128][K1] bf16 row-major (K1 = nch1*32), B1 packed [N/16][K1/32][64][8]
//   A2: [128][2048] bf16 row-major,              B2 packed [N/16][64][64][8]
// Grid: 256 blocks x 256 threads. Block tile 32x32; wave tile 16x16.
// 4 independent accumulator chains (chunk mod 4) to hide MFMA latency at
// 1 wave/SIMD occupancy.
// ---------------------------------------------------------------------------
#define MFMA(a, b, c) __builtin_amdgcn_mfma_f32_16x16x32_bf16((a), (b), (c), 0, 0, 0)

__global__ __launch_bounds__(256) void stage_kernel(
    const __hip_bfloat16* __restrict__ A1, int nch1,
    const short* __restrict__ B1,
    const __hip_bfloat16* __restrict__ A2,
    const short* __restrict__ B2,
    const float* __restrict__ bias,
    __hip_bfloat16* __restrict__ H) {
  const int lane = threadIdx.x & 63;
  const int w    = threadIdx.x >> 6;
  const int Rb   = blockIdx.x >> 6;   // 0..3  (row 32-blocks)
  const int Cb   = blockIdx.x & 63;   // 0..63 (col 32-blocks)
  const int r = Rb * 2 + (w >> 1);    // 16-row tile index, 0..7
  const int c = Cb * 2 + (w & 1);     // 16-col tile index, 0..127
  const int arow = lane & 15;
  const int khi  = (lane >> 4) << 3;

  f32x4 acc0 = {0.f, 0.f, 0.f, 0.f};
  f32x4 acc1 = {0.f, 0.f, 0.f, 0.f};
  f32x4 acc2 = {0.f, 0.f, 0.f, 0.f};
  f32x4 acc3 = {0.f, 0.f, 0.f, 0.f};

  // ---- matmul 1: A1 @ B1, K1 = nch1*32 (nch1 = 4 for layer 0, else 64) ----
  {
    const int K1 = nch1 * 32;
    const short* ap = reinterpret_cast<const short*>(A1) + (r * 16 + arow) * K1 + khi;
    const short* bp = B1 + (size_t)c * nch1 * 512 + lane * 8;
    for (int k = 0; k < nch1; k += 4) {
      bf16x8 a0 = *reinterpret_cast<const bf16x8*>(ap);
      bf16x8 b0 = *reinterpret_cast<const bf16x8*>(bp);
      bf16x8 a1 = *reinterpret_cast<const bf16x8*>(ap + 32);
      bf16x8 b1 = *reinterpret_cast<const bf16x8*>(bp + 512);
      bf16x8 a2 = *reinterpret_cast<const bf16x8*>(ap + 64);
      bf16x8 b2 = *reinterpret_cast<const bf16x8*>(bp + 1024);
      bf16x8 a3 = *reinterpret_cast<const bf16x8*>(ap + 96);
      bf16x8 b3 = *reinterpret_cast<const bf16x8*>(bp + 1536);
      acc0 = MFMA(a0, b0, acc0);
      acc1 = MFMA(a1, b1, acc1);
      acc2 = MFMA(a2, b2, acc2);
      acc3 = MFMA(a3, b3, acc3);
      ap += 128;
      bp += 2048;
    }
  }

  // ---- matmul 2: A2 @ B2, K2 = 2048 (64 chunks) ----
  {
    const short* ap = reinterpret_cast<const short*>(A2) + (r * 16 + arow) * UNITS + khi;
    const short* bp = B2 + (size_t)c * 64 * 512 + lane * 8;
    for (int k = 0; k < 64; k += 4) {
      bf16x8 a0 = *reinterpret_cast<const bf16x8*>(ap);
      bf16x8 b0 = *reinterpret_cast<const bf16x8*>(bp);
      bf16x8 a1 = *reinterpret_cast<const bf16x8*>(ap + 32);
      bf16x8 b1 = *reinterpret_cast<const bf16x8*>(bp + 512);
      bf16x8 a2 = *reinterpret_cast<const bf16x8*>(ap + 64);
      bf16x8 b2 = *reinterpret_cast<const bf16x8*>(bp + 1024);
      bf16x8 a3 = *reinterpret_cast<const bf16x8*>(ap + 96);
      bf16x8 b3 = *reinterpret_cast<const bf16x8*>(bp + 1536);
      acc0 = MFMA(a0, b0, acc0);
      acc1 = MFMA(a1, b1, acc1);
      acc2 = MFMA(a2, b2, acc2);
      acc3 = MFMA(a3, b3, acc3);
      ap += 128;
      bp += 2048;
    }
  }

  f32x4 acc = acc0 + acc1 + acc2 + acc3;

  // Epilogue: bias + tanh + bf16 store. C/D layout: col=lane&15, row=(lane>>4)*4+i
  const int ocol = c * 16 + (lane & 15);
  const float bv = bias[ocol];
  const int orow = r * 16 + ((lane >> 4) << 2);
#pragma unroll
  for (int i = 0; i < 4; ++i) {
    float z = acc[i] + bv;
    H[(orow + i) * UNITS + ocol] = __float2bfloat16(tanhf(z));
  }
}

// ---------------------------------------------------------------------------
// Output head: out[b] = sigmoid(h3[b] . Wo + bo). One block per batch row.
// ---------------------------------------------------------------------------
__global__ __launch_bounds__(256) void head_kernel(
    const __hip_bfloat16* __restrict__ h3, const float* __restrict__ Wo,
    const float* __restrict__ bo, float* __restrict__ out) {
  __shared__ float s[4];
  int b = blockIdx.x;
  int tid = threadIdx.x;
  float acc = 0.f;
#pragma unroll
  for (int i = 0; i < 8; ++i) {
    int n = tid + i * 256;
    acc += __bfloat162float(h3[b * UNITS + n]) * Wo[n];
  }
  for (int off = 32; off > 0; off >>= 1) acc += __shfl_down(acc, off);
  if ((tid & 63) == 0) s[tid >> 6] = acc;
  __syncthreads();
  if (tid == 0) {
    float z = s[0] + s[1] + s[2] + s[3] + bo[0];
    out[b] = 1.f / (1.f + expf(-z));
  }
}

// ---------------------------------------------------------------------------
// Workspace layout (bytes)
// ---------------------------------------------------------------------------
#define W0P_OFF 0u                      // [2048/16][128/32][64][8]  = 512 KB
#define U0P_OFF (W0P_OFF + 128u * 2048u * 2u)
#define W1P_OFF (U0P_OFF + 2048u * 2048u * 2u)
#define U1P_OFF (W1P_OFF + 2048u * 2048u * 2u)
#define E_OFF   (U1P_OFF + 2048u * 2048u * 2u)       // [80][128][128] bf16
#define H_OFF   (E_OFF + (unsigned)(SEQ * BATCH * EPAD) * 2u)  // 8 x [128][2048] bf16

extern "C" void kernel_launch(void* const* d_in, const int* in_sizes, int n_in,
                              void* d_out, int out_size, void* d_ws, size_t ws_size,
                              hipStream_t stream) {
  const int*   tokens = (const int*)d_in[0];
  const float* emb    = (const float*)d_in[1];
  const float* W0     = (const float*)d_in[2];
  const float* U0     = (const float*)d_in[3];
  const float* b0     = (const float*)d_in[4];
  const float* W1     = (const float*)d_in[5];
  const float* U1     = (const float*)d_in[6];
  const float* b1     = (const float*)d_in[7];
  const float* Wo     = (const float*)d_in[8];
  const float* bo     = (const float*)d_in[9];
  float* out = (float*)d_out;
  char*  ws  = (char*)d_ws;

  short* W0p = (short*)(ws + W0P_OFF);
  short* U0p = (short*)(ws + U0P_OFF);
  short* W1p = (short*)(ws + W1P_OFF);
  short* U1p = (short*)(ws + U1P_OFF);
  __hip_bfloat16* E = (__hip_bfloat16*)(ws + E_OFF);
  __hip_bfloat16* hbase = (__hip_bfloat16*)(ws + H_OFF);

  auto hb = [&](int l, int p) { return hbase + (size_t)(l * 2 + p) * (BATCH * UNITS); };

  // ---- pack weights (bf16, B-fragment layout) and embeddings ----
  {
    int unitsW0 = (UNITS / 16) * (EPAD / 32);   // 128*4 = 512
    pack_b_kernel<<<(unitsW0 + 3) / 4, 256, 0, stream>>>(W0, EMB, UNITS, EPAD / 32, unitsW0, W0p);
    int unitsU = (UNITS / 16) * (UNITS / 32);   // 128*64 = 8192
    pack_b_kernel<<<(unitsU + 3) / 4, 256, 0, stream>>>(U0, UNITS, UNITS, UNITS / 32, unitsU, U0p);
    pack_b_kernel<<<(unitsU + 3) / 4, 256, 0, stream>>>(W1, UNITS, UNITS, UNITS / 32, unitsU, W1p);
    pack_b_kernel<<<(unitsU + 3) / 4, 256, 0, stream>>>(U1, UNITS, UNITS, UNITS / 32, unitsU, U1p);
    int ne = SEQ * BATCH * EPAD;
    pack_e_kernel<<<(ne + 255) / 256, 256, 0, stream>>>(tokens, emb, E);
  }

  // zero all 8 h double-buffers (t=0 reads parity-1 buffers)
  hipMemsetAsync(hbase, 0, 8u * BATCH * UNITS * 2u, stream);

  // ---- 80 timesteps x 4 layers ----
  for (int t = 0; t < SEQ; ++t) {
    int cur = t & 1, prv = cur ^ 1;
    const __hip_bfloat16* Et = E + (size_t)t * BATCH * EPAD;
    stage_kernel<<<256, 256, 0, stream>>>(Et,        EPAD / 32,  W0p, hb(0, prv), U0p, b0, hb(0, cur));
    stage_kernel<<<256, 256, 0, stream>>>(hb(0, cur), UNITS / 32, W1p, hb(1, prv), U1p, b1, hb(1, cur));
    stage_kernel<<<256, 256, 0, stream>>>(hb(1, cur), UNITS / 32, W1p, hb(2, prv), U1p, b1, hb(2, cur));
    stage_kernel<<<256, 256, 0, stream>>>(hb(2, cur), UNITS / 32, W1p, hb(3, prv), U1p, b1, hb(3, cur));
  }

  // final head: h3 at parity (SEQ-1)&1 = 1
  head_kernel<<<BATCH, 256, 0, stream>>>(hb(3, 1), Wo, bo, out);
}

// Round 2
// 5448.908 us; speedup vs baseline: 1.0430x; 1.0430x over previous
//
#include <hip/hip_runtime.h>
#include <hip/hip_bf16.h>

#define BATCH 128
#define SEQ   80
#define EMB   100
#define UNITS 2048
#define EPAD  128   // K-pad for the embedding matmul (100 -> 128)

typedef __attribute__((ext_vector_type(8))) short bf16x8;
typedef __attribute__((ext_vector_type(4))) float f32x4;

static __device__ __forceinline__ short f2bf(float f) {
  __hip_bfloat16 h = __float2bfloat16(f);
  return *reinterpret_cast<short*>(&h);
}

// ---------------------------------------------------------------------------
// Pack a row-major fp32 [K][N] weight matrix into MFMA B-operand layout:
// dst[c][kk][lane][j] = bf16(src[kk*32 + (lane>>4)*8 + j][c*16 + (lane&15)])
// Rows k >= Ksrc are zero (K padding for W0).
// ---------------------------------------------------------------------------
__global__ __launch_bounds__(256) void pack_b_kernel(
    const float* __restrict__ src, int Ksrc, int N, int nch, int totalUnits,
    short* __restrict__ dst) {
  int lane = threadIdx.x & 63;
  int u = blockIdx.x * 4 + (threadIdx.x >> 6);
  if (u >= totalUnits) return;
  int c  = u / nch;
  int kk = u - c * nch;
  int n  = c * 16 + (lane & 15);
  int k0 = kk * 32 + ((lane >> 4) << 3);
  bf16x8 v;
#pragma unroll
  for (int j = 0; j < 8; ++j) {
    int k = k0 + j;
    float f = (k < Ksrc) ? src[k * N + n] : 0.f;
    v[j] = f2bf(f);
  }
  *reinterpret_cast<bf16x8*>(dst + (u * 64 + lane) * 8) = v;
}

// ---------------------------------------------------------------------------
// Gather + K-pad embeddings: E[t][b][k] = bf16(emb[tokens[b][t]][k]) (k<100),
// zero for 100 <= k < 128. Row-major [SEQ][BATCH][EPAD].
// ---------------------------------------------------------------------------
__global__ __launch_bounds__(256) void pack_e_kernel(
    const int* __restrict__ tokens, const float* __restrict__ emb,
    __hip_bfloat16* __restrict__ E) {
  int idx = blockIdx.x * 256 + threadIdx.x;
  if (idx >= SEQ * BATCH * EPAD) return;
  int k  = idx & (EPAD - 1);
  int bt = idx >> 7;          // t*BATCH + b
  int b  = bt & (BATCH - 1);
  int t  = bt >> 7;
  int tok = tokens[b * SEQ + t];
  float f = (k < EMB) ? emb[tok * EMB + k] : 0.f;
  E[idx] = __float2bfloat16(f);
}

// ---------------------------------------------------------------------------
// Diagonal-wavefront kernel. Diagonal s computes, concurrently:
//   layer l (l = 0..3) at time t = s - l (if 0 <= t < SEQ):
//     h_l[t] = tanh(A1 @ B1 + h_l[t-1] @ B2 + bias)
//   where A1 = E[t] (l==0, K=128) or h_{l-1}[t] (l>0, K=2048).
// All reads are parity (s-1)&1 buffers; writes go to parity s&1. Every
// operand read was written at diagonal s-1 (or is the zero init), so one
// launch per diagonal is race-free.
//
// Grid: 256 blocks = 8 rowgroups (layer*2 + sub64) x 32 colgroups (64 cols).
// Block: 512 threads = 8 waves; wave (wr,wc) computes rows [sub*64+wr*32, +32)
// x cols [cg*64+wc*16, +16) as 2 accumulator chains sharing each B fragment.
// ---------------------------------------------------------------------------
#define MFMA(a, b, c) __builtin_amdgcn_mfma_f32_16x16x32_bf16((a), (b), (c), 0, 0, 0)

__global__ __launch_bounds__(512) void diag_kernel(
    const short* __restrict__ E,
    const short* __restrict__ W0p, const short* __restrict__ U0p,
    const short* __restrict__ Wsp, const short* __restrict__ Usp,
    const float* __restrict__ b0, const float* __restrict__ b1,
    short* __restrict__ hbase, int s) {
  const int lane = threadIdx.x & 63;
  const int w    = threadIdx.x >> 6;
  const int wr = w >> 2, wc = w & 3;
  const int cg = blockIdx.x & 31, rg = blockIdx.x >> 5;
  const int l = rg >> 1, sub = rg & 1;
  const int t = s - l;
  if (t < 0 || t >= SEQ) return;

  const size_t hsz = (size_t)BATCH * UNITS;
  const int pw = s & 1, pr = pw ^ 1;

  const short* A1; int lda1; int nch1; const short* B1;
  const short* A2; const short* B2; const float* bias;
  if (l == 0) {
    A1 = E + (size_t)t * BATCH * EPAD; lda1 = EPAD; nch1 = EPAD / 32;
    B1 = W0p; B2 = U0p; bias = b0;
    A2 = hbase + (size_t)(0 * 2 + pr) * hsz;
  } else {
    A1 = hbase + (size_t)((l - 1) * 2 + pr) * hsz; lda1 = UNITS; nch1 = UNITS / 32;
    B1 = Wsp; B2 = Usp; bias = b1;
    A2 = hbase + (size_t)(l * 2 + pr) * hsz;
  }
  short* H = hbase + (size_t)(l * 2 + pw) * hsz;

  const int rowbase = sub * 64 + wr * 32;
  const int ct = cg * 4 + wc;          // global 16-col tile index
  const int arow = lane & 15;
  const int khi  = (lane >> 4) << 3;

  f32x4 acc0 = {0.f, 0.f, 0.f, 0.f};
  f32x4 acc1 = {0.f, 0.f, 0.f, 0.f};

  // ---- matmul 1: A1 @ B1 (K = nch1*32) ----
  {
    const short* ap0 = A1 + (rowbase + arow) * lda1 + khi;
    const short* ap1 = ap0 + 16 * lda1;
    const short* bp  = B1 + (size_t)ct * nch1 * 512 + lane * 8;
    for (int kk = 0; kk < nch1; kk += 4) {
      bf16x8 a00 = *(const bf16x8*)ap0;
      bf16x8 a10 = *(const bf16x8*)ap1;
      bf16x8 bv0 = *(const bf16x8*)bp;
      bf16x8 a01 = *(const bf16x8*)(ap0 + 32);
      bf16x8 a11 = *(const bf16x8*)(ap1 + 32);
      bf16x8 bv1 = *(const bf16x8*)(bp + 512);
      bf16x8 a02 = *(const bf16x8*)(ap0 + 64);
      bf16x8 a12 = *(const bf16x8*)(ap1 + 64);
      bf16x8 bv2 = *(const bf16x8*)(bp + 1024);
      bf16x8 a03 = *(const bf16x8*)(ap0 + 96);
      bf16x8 a13 = *(const bf16x8*)(ap1 + 96);
      bf16x8 bv3 = *(const bf16x8*)(bp + 1536);
      acc0 = MFMA(a00, bv0, acc0);
      acc1 = MFMA(a10, bv0, acc1);
      acc0 = MFMA(a01, bv1, acc0);
      acc1 = MFMA(a11, bv1, acc1);
      acc0 = MFMA(a02, bv2, acc0);
      acc1 = MFMA(a12, bv2, acc1);
      acc0 = MFMA(a03, bv3, acc0);
      acc1 = MFMA(a13, bv3, acc1);
      ap0 += 128; ap1 += 128; bp += 2048;
    }
  }

  // ---- matmul 2: h_l[t-1] @ B2 (K = 2048, 64 chunks) ----
  {
    const short* ap0 = A2 + (rowbase + arow) * UNITS + khi;
    const short* ap1 = ap0 + 16 * UNITS;
    const short* bp  = B2 + (size_t)ct * 64 * 512 + lane * 8;
    for (int kk = 0; kk < 64; kk += 4) {
      bf16x8 a00 = *(const bf16x8*)ap0;
      bf16x8 a10 = *(const bf16x8*)ap1;
      bf16x8 bv0 = *(const bf16x8*)bp;
      bf16x8 a01 = *(const bf16x8*)(ap0 + 32);
      bf16x8 a11 = *(const bf16x8*)(ap1 + 32);
      bf16x8 bv1 = *(const bf16x8*)(bp + 512);
      bf16x8 a02 = *(const bf16x8*)(ap0 + 64);
      bf16x8 a12 = *(const bf16x8*)(ap1 + 64);
      bf16x8 bv2 = *(const bf16x8*)(bp + 1024);
      bf16x8 a03 = *(const bf16x8*)(ap0 + 96);
      bf16x8 a13 = *(const bf16x8*)(ap1 + 96);
      bf16x8 bv3 = *(const bf16x8*)(bp + 1536);
      acc0 = MFMA(a00, bv0, acc0);
      acc1 = MFMA(a10, bv0, acc1);
      acc0 = MFMA(a01, bv1, acc0);
      acc1 = MFMA(a11, bv1, acc1);
      acc0 = MFMA(a02, bv2, acc0);
      acc1 = MFMA(a12, bv2, acc1);
      acc0 = MFMA(a03, bv3, acc0);
      acc1 = MFMA(a13, bv3, acc1);
      ap0 += 128; ap1 += 128; bp += 2048;
    }
  }

  // Epilogue: bias + tanh + bf16 store. C/D layout: col=lane&15, row=(lane>>4)*4+i
  const int ocol = ct * 16 + (lane & 15);
  const float bv = bias[ocol];
  const int orow0 = rowbase + ((lane >> 4) << 2);
#pragma unroll
  for (int i = 0; i < 4; ++i) {
    H[(orow0 + i) * UNITS + ocol]      = f2bf(tanhf(acc0[i] + bv));
    H[(orow0 + 16 + i) * UNITS + ocol] = f2bf(tanhf(acc1[i] + bv));
  }
}

// ---------------------------------------------------------------------------
// Output head: out[b] = sigmoid(h3[b] . Wo + bo). One block per batch row.
// ---------------------------------------------------------------------------
__global__ __launch_bounds__(256) void head_kernel(
    const __hip_bfloat16* __restrict__ h3, const float* __restrict__ Wo,
    const float* __restrict__ bo, float* __restrict__ out) {
  __shared__ float s[4];
  int b = blockIdx.x;
  int tid = threadIdx.x;
  float acc = 0.f;
#pragma unroll
  for (int i = 0; i < 8; ++i) {
    int n = tid + i * 256;
    acc += __bfloat162float(h3[b * UNITS + n]) * Wo[n];
  }
  for (int off = 32; off > 0; off >>= 1) acc += __shfl_down(acc, off);
  if ((tid & 63) == 0) s[tid >> 6] = acc;
  __syncthreads();
  if (tid == 0) {
    float z = s[0] + s[1] + s[2] + s[3] + bo[0];
    out[b] = 1.f / (1.f + expf(-z));
  }
}

// ---------------------------------------------------------------------------
// Workspace layout (bytes)
// ---------------------------------------------------------------------------
#define W0P_OFF 0u
#define U0P_OFF (W0P_OFF + 128u * 2048u * 2u)
#define W1P_OFF (U0P_OFF + 2048u * 2048u * 2u)
#define U1P_OFF (W1P_OFF + 2048u * 2048u * 2u)
#define E_OFF   (U1P_OFF + 2048u * 2048u * 2u)       // [80][128][128] bf16
#define H_OFF   (E_OFF + (unsigned)(SEQ * BATCH * EPAD) * 2u)  // 8 x [128][2048] bf16

extern "C" void kernel_launch(void* const* d_in, const int* in_sizes, int n_in,
                              void* d_out, int out_size, void* d_ws, size_t ws_size,
                              hipStream_t stream) {
  const int*   tokens = (const int*)d_in[0];
  const float* emb    = (const float*)d_in[1];
  const float* W0     = (const float*)d_in[2];
  const float* U0     = (const float*)d_in[3];
  const float* b0     = (const float*)d_in[4];
  const float* W1     = (const float*)d_in[5];
  const float* U1     = (const float*)d_in[6];
  const float* b1     = (const float*)d_in[7];
  const float* Wo     = (const float*)d_in[8];
  const float* bo     = (const float*)d_in[9];
  float* out = (float*)d_out;
  char*  ws  = (char*)d_ws;

  short* W0p = (short*)(ws + W0P_OFF);
  short* U0p = (short*)(ws + U0P_OFF);
  short* W1p = (short*)(ws + W1P_OFF);
  short* U1p = (short*)(ws + U1P_OFF);
  short* E   = (short*)(ws + E_OFF);
  short* hbase = (short*)(ws + H_OFF);
  const size_t hsz = (size_t)BATCH * UNITS;

  // ---- pack weights (bf16, B-fragment layout) and embeddings ----
  {
    int unitsW0 = (UNITS / 16) * (EPAD / 32);   // 512
    pack_b_kernel<<<(unitsW0 + 3) / 4, 256, 0, stream>>>(W0, EMB, UNITS, EPAD / 32, unitsW0, W0p);
    int unitsU = (UNITS / 16) * (UNITS / 32);   // 8192
    pack_b_kernel<<<(unitsU + 3) / 4, 256, 0, stream>>>(U0, UNITS, UNITS, UNITS / 32, unitsU, U0p);
    pack_b_kernel<<<(unitsU + 3) / 4, 256, 0, stream>>>(W1, UNITS, UNITS, UNITS / 32, unitsU, W1p);
    pack_b_kernel<<<(unitsU + 3) / 4, 256, 0, stream>>>(U1, UNITS, UNITS, UNITS / 32, unitsU, U1p);
    int ne = SEQ * BATCH * EPAD;
    pack_e_kernel<<<(ne + 255) / 256, 256, 0, stream>>>(tokens, emb, (__hip_bfloat16*)E);
  }

  // zero all 8 h double-buffers (diagonal s reads parity (s-1)&1; the zero
  // init provides h_l[-1] = 0 for every layer's first step)
  hipMemsetAsync(hbase, 0, 8u * BATCH * UNITS * 2u, stream);

  // ---- 83 diagonals: s = t + l ----
  for (int s = 0; s <= SEQ - 1 + 3; ++s) {
    diag_kernel<<<256, 512, 0, stream>>>(E, W0p, U0p, W1p, U1p, b0, b1, hbase, s);
  }

  // final head: h3[SEQ-1] written at diagonal s = SEQ-1+3 = 82, parity 0
  head_kernel<<<BATCH, 256, 0, stream>>>((const __hip_bfloat16*)(hbase + 6 * hsz), Wo, bo, out);
}

// Round 3
// 2336.693 us; speedup vs baseline: 2.4322x; 2.3319x over previous
//
#include <hip/hip_runtime.h>
#include <hip/hip_bf16.h>

#define BATCH 128
#define SEQ   80
#define EMB   100
#define UNITS 2048
#define EPAD  128   // K-pad for the embedding matmul (100 -> 128)

typedef __attribute__((ext_vector_type(8))) short bf16x8;
typedef __attribute__((ext_vector_type(4))) float f32x4;

static __device__ __forceinline__ short f2bf(float f) {
  __hip_bfloat16 h = __float2bfloat16(f);
  return *reinterpret_cast<short*>(&h);
}
static __device__ __forceinline__ float bf2f(short s) {
  __hip_bfloat16 h = *reinterpret_cast<__hip_bfloat16*>(&s);
  return __bfloat162float(h);
}

// Packed fragment layouts (nch = K/32):
//  A-pack (h state, E): elem(row m, k) at [r=m>>4][kk=k>>5][lane=(m&15)|(((k>>3)&3)<<4)][j=k&7]
//  B-pack (weights):    elem(k, col n) at [c=n>>4][kk=k>>5][lane=(n&15)|(((k>>3)&3)<<4)][j=k&7]
// Both are [..][64 lanes][8] units of 1 KB; staging is a linear 16B/lane copy.

// ---------------------------------------------------------------------------
// Pack a row-major fp32 [K][N] weight into B-pack. One wave per (c,kk) unit.
// ---------------------------------------------------------------------------
__global__ __launch_bounds__(256) void pack_b_kernel(
    const float* __restrict__ src, int Ksrc, int N, int nch, int totalUnits,
    short* __restrict__ dst) {
  int lane = threadIdx.x & 63;
  int u = blockIdx.x * 4 + (threadIdx.x >> 6);
  if (u >= totalUnits) return;
  int c  = u / nch;
  int kk = u - c * nch;
  int n  = c * 16 + (lane & 15);
  int k0 = kk * 32 + ((lane >> 4) << 3);
  bf16x8 v;
#pragma unroll
  for (int j = 0; j < 8; ++j) {
    int k = k0 + j;
    float f = (k < Ksrc) ? src[k * N + n] : 0.f;
    v[j] = f2bf(f);
  }
  *reinterpret_cast<bf16x8*>(dst + (u * 64 + lane) * 8) = v;
}

// ---------------------------------------------------------------------------
// Gather + K-pad embeddings directly into A-pack layout per timestep:
// Ep[t][r][kk][lane][8], 8 r-tiles x 4 kk-chunks. One thread per 16B unit.
// ---------------------------------------------------------------------------
__global__ __launch_bounds__(256) void pack_e_kernel(
    const int* __restrict__ tokens, const float* __restrict__ emb,
    short* __restrict__ Ep) {
  int idx = blockIdx.x * 256 + threadIdx.x;   // (t,r,kk,lane)
  if (idx >= SEQ * 8 * 4 * 64) return;
  int lane = idx & 63;
  int kk = (idx >> 6) & 3;
  int r  = (idx >> 8) & 7;
  int t  = idx >> 11;
  int b  = r * 16 + (lane & 15);
  int k0 = kk * 32 + ((lane >> 4) << 3);
  int tok = tokens[b * SEQ + t];
  bf16x8 v;
#pragma unroll
  for (int j = 0; j < 8; ++j) {
    int k = k0 + j;
    v[j] = (k < EMB) ? f2bf(emb[tok * EMB + k]) : (short)0;
  }
  *reinterpret_cast<bf16x8*>(Ep + (size_t)idx * 8) = v;
}

// ---------------------------------------------------------------------------
// Diagonal-wavefront GEMM stage, 2-phase global_load_lds pipeline.
// Diagonal s: layer l at t = s - l computes h_l[t] = tanh(A1@B1 + A2@B2 + b).
// Block = 64x64 output tile (4 waves x 32x32), BK=128 (4 kk-chunks)/step,
// double-buffered LDS (2 x (16+16) KB). A and B staged as linear 16B copies.
// ---------------------------------------------------------------------------
#define MFMA(a, b, c) __builtin_amdgcn_mfma_f32_16x16x32_bf16((a), (b), (c), 0, 0, 0)

static __device__ __forceinline__ void gload16(const void* g, void* l) {
  __builtin_amdgcn_global_load_lds(
      (const __attribute__((address_space(1))) void*)g,
      (__attribute__((address_space(3))) void*)l, 16, 0, 0);
}

// stage one BK=128 step: A 16KB + B 16KB, 4 rounds x 256 threads x 16B each
static __device__ __forceinline__ void stage_step(
    const short* __restrict__ Ab, const short* __restrict__ Bb, int nch, int kk0,
    int rloc0, int ct0, int tid, bf16x8* ldsA, bf16x8* ldsB) {
  const int lane = tid & 63;
#pragma unroll
  for (int rnd = 0; rnd < 4; ++rnd) {
    int s  = rnd * 256 + tid;          // slot = (rt*4 + kq)*64 + lane
    int rt = s >> 8;
    int kq = (s >> 6) & 3;
    const short* ga = Ab + ((size_t)((rloc0 + rt) * nch + kk0 + kq) * 64 + lane) * 8;
    const short* gb = Bb + ((size_t)((ct0 + rt) * nch + kk0 + kq) * 64 + lane) * 8;
    gload16(ga, (char*)ldsA + (size_t)s * 16);
    gload16(gb, (char*)ldsB + (size_t)s * 16);
  }
}

__global__ __launch_bounds__(256) void diag_kernel(
    const short* __restrict__ Ep,
    const short* __restrict__ W0p, const short* __restrict__ U0p,
    const short* __restrict__ Wsp, const short* __restrict__ Usp,
    const float* __restrict__ b0, const float* __restrict__ b1,
    short* __restrict__ hbase, int s) {
  __shared__ bf16x8 As[2][1024];   // [buf][ (rt*4+kq)*64 + lane ]
  __shared__ bf16x8 Bs[2][1024];

  const int tid  = threadIdx.x;
  const int lane = tid & 63;
  const int w    = tid >> 6;

  // XCD-affine swizzle: each XCD gets 4 consecutive cb's x all 8 rb's
  int bid = blockIdx.x;
  int xcd = bid & 7, idx = bid >> 3;
  int cb  = xcd * 4 + (idx & 3);   // 0..31
  int rb  = idx >> 2;              // 0..7
  int l   = rb >> 1;
  int t   = s - l;
  if (t < 0 || t >= SEQ) return;

  const size_t hsz = (size_t)8 * 64 * 64 * 8;   // 262144 elems per h buffer
  const int pw = s & 1, pr = pw ^ 1;
  auto hb = [&](int ll, int p) { return hbase + (size_t)(ll * 2 + p) * hsz; };

  const short *A1, *B1, *A2, *B2;
  const float* bias;
  int nch1;
  if (l == 0) {
    A1 = Ep + (size_t)t * 16384; B1 = W0p; nch1 = 4;
    A2 = hb(0, pr); B2 = U0p; bias = b0;
  } else {
    A1 = hb(l - 1, pr); B1 = Wsp; nch1 = 64;
    A2 = hb(l, pr);     B2 = Usp; bias = b1;
  }
  const int rloc0 = (rb & 1) * 4;    // layer-local r-tile base
  const int ct0   = cb * 4;          // global c-tile base
  const int s0    = nch1 / 4;        // steps in segment 0 (1 or 16)
  const int total = s0 + 16;

  f32x4 acc[2][2];
#pragma unroll
  for (int x = 0; x < 2; ++x)
#pragma unroll
    for (int y = 0; y < 2; ++y) acc[x][y] = (f32x4){0.f, 0.f, 0.f, 0.f};

  // prologue: stage step 0
  stage_step(A1, B1, nch1, 0, rloc0, ct0, tid, &As[0][0], &Bs[0][0]);
  __syncthreads();   // drains vmcnt -> buf0 ready

  const int rt0 = (w & 1) * 2;
  const int ctw = (w >> 1) * 2;
  int cur = 0;

  for (int g = 0; g < total; ++g) {
    // issue next-step staging into the other buffer
    if (g + 1 < total) {
      int gs = g + 1;
      const short *Ab, *Bb; int nch, kk0;
      if (gs < s0) { Ab = A1; Bb = B1; nch = nch1; kk0 = gs * 4; }
      else         { Ab = A2; Bb = B2; nch = 64;   kk0 = (gs - s0) * 4; }
      stage_step(Ab, Bb, nch, kk0, rloc0, ct0, tid, &As[cur ^ 1][0], &Bs[cur ^ 1][0]);
    }
    // compute current buffer: 16 ds_read_b128 + 16 MFMA per wave
    bf16x8 av[2][4], bv[2][4];
#pragma unroll
    for (int x = 0; x < 2; ++x)
#pragma unroll
      for (int kq = 0; kq < 4; ++kq) {
        av[x][kq] = As[cur][((rt0 + x) * 4 + kq) * 64 + lane];
        bv[x][kq] = Bs[cur][((ctw + x) * 4 + kq) * 64 + lane];
      }
#pragma unroll
    for (int kq = 0; kq < 4; ++kq)
#pragma unroll
      for (int x = 0; x < 2; ++x)
#pragma unroll
        for (int y = 0; y < 2; ++y)
          acc[x][y] = MFMA(av[x][kq], bv[y][kq], acc[x][y]);
    __syncthreads();   // drains vmcnt (next buf staged) + lgkm; barrier
    cur ^= 1;
  }

  // Epilogue: bias + tanh, store into A-pack layout of h_l (parity pw).
  // C/D layout: col = lane&15, row = (lane>>4)*4 + i.
  short* H = hb(l, pw);
  const int lo = lane & 15, hi = lane >> 4;
  const int mb = (rb & 1) * 64 + (w & 1) * 32;   // layer-local row base
  const int nb = cb * 64 + (w >> 1) * 32;        // col base
  const float bv0 = bias[nb + lo];
  const float bv1 = bias[nb + 16 + lo];
#pragma unroll
  for (int x = 0; x < 2; ++x)
#pragma unroll
    for (int y = 0; y < 2; ++y) {
      float bbv = y ? bv1 : bv0;
#pragma unroll
      for (int i = 0; i < 4; ++i) {
        int m = mb + x * 16 + hi * 4 + i;
        int n = nb + y * 16 + lo;
        float z = acc[x][y][i] + bbv;
        float e = __expf(2.f * z);
        float th = 1.f - 2.f / (e + 1.f);
        int r  = m >> 4, kk = n >> 5;
        int lp = (m & 15) | (((n >> 3) & 3) << 4);
        H[(((size_t)r * 64 + kk) * 64 + lp) * 8 + (n & 7)] = f2bf(th);
      }
    }
}

// ---------------------------------------------------------------------------
// Output head: out[b] = sigmoid(h3[b] . Wo + bo); h3 in A-pack layout.
// ---------------------------------------------------------------------------
__global__ __launch_bounds__(256) void head_kernel(
    const short* __restrict__ h3, const float* __restrict__ Wo,
    const float* __restrict__ bo, float* __restrict__ out) {
  __shared__ float sred[4];
  int b = blockIdx.x, tid = threadIdx.x;
  int kk = tid >> 2, hi = tid & 3;
  const bf16x8 v = *reinterpret_cast<const bf16x8*>(
      h3 + (((size_t)(b >> 4) * 64 + kk) * 64 + ((b & 15) | (hi << 4))) * 8);
  int k0 = kk * 32 + hi * 8;
  float acc = 0.f;
#pragma unroll
  for (int j = 0; j < 8; ++j) acc += bf2f(v[j]) * Wo[k0 + j];
  for (int off = 32; off > 0; off >>= 1) acc += __shfl_down(acc, off);
  if ((tid & 63) == 0) sred[tid >> 6] = acc;
  __syncthreads();
  if (tid == 0) {
    float z = sred[0] + sred[1] + sred[2] + sred[3] + bo[0];
    out[b] = 1.f / (1.f + expf(-z));
  }
}

// ---------------------------------------------------------------------------
// Workspace layout (shorts)
// ---------------------------------------------------------------------------
extern "C" void kernel_launch(void* const* d_in, const int* in_sizes, int n_in,
                              void* d_out, int out_size, void* d_ws, size_t ws_size,
                              hipStream_t stream) {
  const int*   tokens = (const int*)d_in[0];
  const float* emb    = (const float*)d_in[1];
  const float* W0     = (const float*)d_in[2];
  const float* U0     = (const float*)d_in[3];
  const float* b0     = (const float*)d_in[4];
  const float* W1     = (const float*)d_in[5];
  const float* U1     = (const float*)d_in[6];
  const float* b1     = (const float*)d_in[7];
  const float* Wo     = (const float*)d_in[8];
  const float* bo     = (const float*)d_in[9];
  float* out = (float*)d_out;
  short* ws  = (short*)d_ws;

  const size_t W0P_SZ = (size_t)128 * 4 * 512;     // 262144
  const size_t UP_SZ  = (size_t)128 * 64 * 512;    // 4194304
  const size_t EP_SZ  = (size_t)SEQ * 16384;       // 1310720
  const size_t H_SZ   = (size_t)8 * 64 * 64 * 8;   // 262144 per buffer

  short* W0p = ws;
  short* U0p = W0p + W0P_SZ;
  short* W1p = U0p + UP_SZ;
  short* U1p = W1p + UP_SZ;
  short* Ep  = U1p + UP_SZ;
  short* hbase = Ep + EP_SZ;

  // ---- pack weights + embeddings ----
  {
    int unitsW0 = (UNITS / 16) * (EPAD / 32);   // 512
    pack_b_kernel<<<(unitsW0 + 3) / 4, 256, 0, stream>>>(W0, EMB, UNITS, EPAD / 32, unitsW0, W0p);
    int unitsU = (UNITS / 16) * (UNITS / 32);   // 8192
    pack_b_kernel<<<(unitsU + 3) / 4, 256, 0, stream>>>(U0, UNITS, UNITS, UNITS / 32, unitsU, U0p);
    pack_b_kernel<<<(unitsU + 3) / 4, 256, 0, stream>>>(W1, UNITS, UNITS, UNITS / 32, unitsU, W1p);
    pack_b_kernel<<<(unitsU + 3) / 4, 256, 0, stream>>>(U1, UNITS, UNITS, UNITS / 32, unitsU, U1p);
    int ne = SEQ * 8 * 4 * 64;
    pack_e_kernel<<<(ne + 255) / 256, 256, 0, stream>>>(tokens, emb, Ep);
  }

  // zero all 8 h double-buffers (provides h_l[-1] = 0)
  hipMemsetAsync(hbase, 0, 8u * H_SZ * 2u, stream);

  // ---- 83 diagonals: s = t + l ----
  for (int s = 0; s <= SEQ - 1 + 3; ++s) {
    diag_kernel<<<256, 256, 0, stream>>>(Ep, W0p, U0p, W1p, U1p, b0, b1, hbase, s);
  }

  // final head: h3[SEQ-1] written at diagonal 82 (parity 0)
  head_kernel<<<BATCH, 256, 0, stream>>>(hbase + 6 * H_SZ, Wo, bo, out);
}

// Round 4
// 1596.537 us; speedup vs baseline: 3.5598x; 1.4636x over previous
//
#include <hip/hip_runtime.h>
#include <hip/hip_bf16.h>

#define BATCH 128
#define SEQ   80
#define EMB   100
#define UNITS 2048
#define EPAD  128   // K-pad for the embedding matmul (100 -> 128)

typedef __attribute__((ext_vector_type(8))) short bf16x8;
typedef __attribute__((ext_vector_type(4))) float f32x4;

static __device__ __forceinline__ short f2bf(float f) {
  __hip_bfloat16 h = __float2bfloat16(f);
  return *reinterpret_cast<short*>(&h);
}
static __device__ __forceinline__ float bf2f(short s) {
  __hip_bfloat16 h = *reinterpret_cast<__hip_bfloat16*>(&s);
  return __bfloat162float(h);
}

// Packed fragment layouts (nch = K/32):
//  A-pack (h state, E): elem(row m, k) at [r=m>>4][kk=k>>5][lane=(m&15)|(((k>>3)&3)<<4)][j=k&7]
//  B-pack (weights):    elem(k, col n) at [c=n>>4][kk=k>>5][lane=(n&15)|(((k>>3)&3)<<4)][j=k&7]
// Both are [..][64 lanes][8] units of 1 KB; staging is a linear 16B/lane copy.

__global__ __launch_bounds__(256) void pack_b_kernel(
    const float* __restrict__ src, int Ksrc, int N, int nch, int totalUnits,
    short* __restrict__ dst) {
  int lane = threadIdx.x & 63;
  int u = blockIdx.x * 4 + (threadIdx.x >> 6);
  if (u >= totalUnits) return;
  int c  = u / nch;
  int kk = u - c * nch;
  int n  = c * 16 + (lane & 15);
  int k0 = kk * 32 + ((lane >> 4) << 3);
  bf16x8 v;
#pragma unroll
  for (int j = 0; j < 8; ++j) {
    int k = k0 + j;
    float f = (k < Ksrc) ? src[k * N + n] : 0.f;
    v[j] = f2bf(f);
  }
  *reinterpret_cast<bf16x8*>(dst + (u * 64 + lane) * 8) = v;
}

__global__ __launch_bounds__(256) void pack_e_kernel(
    const int* __restrict__ tokens, const float* __restrict__ emb,
    short* __restrict__ Ep) {
  int idx = blockIdx.x * 256 + threadIdx.x;   // (t,r,kk,lane)
  if (idx >= SEQ * 8 * 4 * 64) return;
  int lane = idx & 63;
  int kk = (idx >> 6) & 3;
  int r  = (idx >> 8) & 7;
  int t  = idx >> 11;
  int b  = r * 16 + (lane & 15);
  int k0 = kk * 32 + ((lane >> 4) << 3);
  int tok = tokens[b * SEQ + t];
  bf16x8 v;
#pragma unroll
  for (int j = 0; j < 8; ++j) {
    int k = k0 + j;
    v[j] = (k < EMB) ? f2bf(emb[tok * EMB + k]) : (short)0;
  }
  *reinterpret_cast<bf16x8*>(Ep + (size_t)idx * 8) = v;
}

// ---------------------------------------------------------------------------
// Diagonal-wavefront GEMM stage with ring-4 LDS pipeline + counted vmcnt.
// Block = 64x64 tile (4 waves x 32x32), BK=128 (4 kk-chunks)/step.
// Per step: stage 32 KB (A 16 + B 16) via 8 gload_lds(16B)/thread; steady
// state keeps 3 steps (24 vmem instrs/wave) in flight; never drains to 0.
// ---------------------------------------------------------------------------
#define MFMA(a, b, c) __builtin_amdgcn_mfma_f32_16x16x32_bf16((a), (b), (c), 0, 0, 0)

static __device__ __forceinline__ void gload16(const void* g, void* l) {
  __builtin_amdgcn_global_load_lds(
      (const __attribute__((address_space(1))) void*)g,
      (__attribute__((address_space(3))) void*)l, 16, 0, 0);
}

// stage 4 A-units + 4 B-units for this thread (r = 0..3)
static __device__ __forceinline__ void stage8(
    char* ldsA, const char* gA, size_t strA,
    char* ldsB, const char* gB, size_t strB) {
#pragma unroll
  for (int r = 0; r < 4; ++r) {
    gload16(gA + r * strA, ldsA + r * 4096);
    gload16(gB + r * strB, ldsB + r * 4096);
  }
}

__global__ __launch_bounds__(256) void diag_kernel(
    const short* __restrict__ Ep,
    const short* __restrict__ W0p, const short* __restrict__ U0p,
    const short* __restrict__ Wsp, const short* __restrict__ Usp,
    const float* __restrict__ b0, const float* __restrict__ b1,
    short* __restrict__ hbase, int s) {
  __shared__ char lds[4][32768];   // ring of 4: [A 16KB][B 16KB] each

  const int tid  = threadIdx.x;
  const int lane = tid & 63;
  const int w    = tid >> 6;       // 0..3  (== kq this thread stages)
  const int wr   = w & 1, wc = w >> 1;

  // XCD-affine mapping: xcd = bid & 7 owns 4 consecutive cb's x all rb's
  int bid = blockIdx.x;
  int xcd = bid & 7, idx = bid >> 3;
  int cb  = xcd * 4 + (idx & 3);   // 0..31
  int rb  = idx >> 2;              // 0..7
  int l   = rb >> 1;
  int t   = s - l;
  if (t < 0 || t >= SEQ) return;

  const size_t hsz = (size_t)8 * 64 * 64 * 8;
  const int pw = s & 1, pr = pw ^ 1;
  auto hb = [&](int ll, int p) { return hbase + (size_t)(ll * 2 + p) * hsz; };

  const short *A1, *B1, *A2, *B2;
  const float* bias;
  int steps0, str1;
  if (l == 0) {
    A1 = Ep + (size_t)t * 16384; B1 = W0p; steps0 = 1;  str1 = 4096;
    A2 = hb(0, pr); B2 = U0p; bias = b0;
  } else {
    A1 = hb(l - 1, pr); B1 = Wsp; steps0 = 16; str1 = 65536;
    A2 = hb(l, pr);     B2 = Usp; bias = b1;
  }
  const int rloc0 = (rb & 1) * 4;    // layer-local r-tile base
  const int ct0   = cb * 4;          // global c-tile base
  const int total = steps0 + 16;

  // per-thread global base pointers (byte), unit (row r) stride given per seg
  const size_t koffq = (size_t)w * 1024 + (size_t)lane * 16;
  const char* a1p = (const char*)A1 + (size_t)rloc0 * (size_t)str1 + koffq;
  const char* b1p = (const char*)B1 + (size_t)ct0   * (size_t)str1 + koffq;
  const char* a2p = (const char*)A2 + (size_t)rloc0 * 65536 + koffq;
  const char* b2p = (const char*)B2 + (size_t)ct0   * 65536 + koffq;

  char* ldsA0 = &lds[0][0] + (size_t)tid * 16;
  char* ldsB0 = ldsA0 + 16384;

  auto issue = [&](int g) {
    char* la = ldsA0 + (size_t)(g & 3) * 32768;
    char* lb = ldsB0 + (size_t)(g & 3) * 32768;
    if (g < steps0) {
      size_t kb = (size_t)g * 4096;
      stage8(la, a1p + kb, (size_t)str1, lb, b1p + kb, (size_t)str1);
    } else {
      size_t kb = (size_t)(g - steps0) * 4096;
      stage8(la, a2p + kb, 65536, lb, b2p + kb, 65536);
    }
  };

  f32x4 acc[2][2];
#pragma unroll
  for (int x = 0; x < 2; ++x)
#pragma unroll
    for (int y = 0; y < 2; ++y) acc[x][y] = (f32x4){0.f, 0.f, 0.f, 0.f};

  auto compute = [&](int g) {
    const char* base = &lds[g & 3][0];
    bf16x8 av[2][4], bv[2][4];
#pragma unroll
    for (int x = 0; x < 2; ++x)
#pragma unroll
      for (int kq = 0; kq < 4; ++kq) {
        av[x][kq] = *(const bf16x8*)(base + ((((wr * 2 + x) * 4 + kq) * 64 + lane) << 4));
        bv[x][kq] = *(const bf16x8*)(base + 16384 + ((((wc * 2 + x) * 4 + kq) * 64 + lane) << 4));
      }
#pragma unroll
    for (int kq = 0; kq < 4; ++kq)
#pragma unroll
      for (int x = 0; x < 2; ++x)
#pragma unroll
        for (int y = 0; y < 2; ++y)
          acc[x][y] = MFMA(av[x][kq], bv[y][kq], acc[x][y]);
  };

  // prime 3 steps (24 vmem instrs in flight)
  issue(0); issue(1); issue(2);

  for (int g = 0; g + 3 < total; ++g) {
    issue(g + 3);                                      // 32 in flight
    asm volatile("s_waitcnt vmcnt(24)" ::: "memory");  // step g's 8 done
    __builtin_amdgcn_s_barrier();                      // all waves' step g done
    __builtin_amdgcn_sched_barrier(0);
    compute(g);
    __builtin_amdgcn_sched_barrier(0);
    __builtin_amdgcn_s_barrier();                      // slot g&3 free for reuse
  }
  // tail: 3 remaining steps
  asm volatile("s_waitcnt vmcnt(16)" ::: "memory");
  __builtin_amdgcn_s_barrier();
  __builtin_amdgcn_sched_barrier(0);
  compute(total - 3);
  __builtin_amdgcn_sched_barrier(0);
  __builtin_amdgcn_s_barrier();
  asm volatile("s_waitcnt vmcnt(8)" ::: "memory");
  __builtin_amdgcn_s_barrier();
  __builtin_amdgcn_sched_barrier(0);
  compute(total - 2);
  __builtin_amdgcn_sched_barrier(0);
  __builtin_amdgcn_s_barrier();
  asm volatile("s_waitcnt vmcnt(0)" ::: "memory");
  __builtin_amdgcn_s_barrier();
  __builtin_amdgcn_sched_barrier(0);
  compute(total - 1);

  // Epilogue: bias + tanh, store into A-pack layout of h_l (parity pw).
  // C/D layout: col = lane&15, row = (lane>>4)*4 + i.
  short* H = hb(l, pw);
  const int lo = lane & 15, hi = lane >> 4;
  const int mb = (rb & 1) * 64 + wr * 32;
  const int nb = cb * 64 + wc * 32;
  const float bv0 = bias[nb + lo];
  const float bv1 = bias[nb + 16 + lo];
#pragma unroll
  for (int x = 0; x < 2; ++x)
#pragma unroll
    for (int y = 0; y < 2; ++y) {
      float bbv = y ? bv1 : bv0;
#pragma unroll
      for (int i = 0; i < 4; ++i) {
        int m = mb + x * 16 + hi * 4 + i;
        int n = nb + y * 16 + lo;
        float z = acc[x][y][i] + bbv;
        float e = __expf(2.f * z);
        float th = 1.f - 2.f / (e + 1.f);
        int r  = m >> 4, kk = n >> 5;
        int lp = (m & 15) | (((n >> 3) & 3) << 4);
        H[(((size_t)r * 64 + kk) * 64 + lp) * 8 + (n & 7)] = f2bf(th);
      }
    }
}

// ---------------------------------------------------------------------------
// Output head: out[b] = sigmoid(h3[b] . Wo + bo); h3 in A-pack layout.
// ---------------------------------------------------------------------------
__global__ __launch_bounds__(256) void head_kernel(
    const short* __restrict__ h3, const float* __restrict__ Wo,
    const float* __restrict__ bo, float* __restrict__ out) {
  __shared__ float sred[4];
  int b = blockIdx.x, tid = threadIdx.x;
  int kk = tid >> 2, hi = tid & 3;
  const bf16x8 v = *reinterpret_cast<const bf16x8*>(
      h3 + (((size_t)(b >> 4) * 64 + kk) * 64 + ((b & 15) | (hi << 4))) * 8);
  int k0 = kk * 32 + hi * 8;
  float acc = 0.f;
#pragma unroll
  for (int j = 0; j < 8; ++j) acc += bf2f(v[j]) * Wo[k0 + j];
  for (int off = 32; off > 0; off >>= 1) acc += __shfl_down(acc, off);
  if ((tid & 63) == 0) sred[tid >> 6] = acc;
  __syncthreads();
  if (tid == 0) {
    float z = sred[0] + sred[1] + sred[2] + sred[3] + bo[0];
    out[b] = 1.f / (1.f + expf(-z));
  }
}

extern "C" void kernel_launch(void* const* d_in, const int* in_sizes, int n_in,
                              void* d_out, int out_size, void* d_ws, size_t ws_size,
                              hipStream_t stream) {
  const int*   tokens = (const int*)d_in[0];
  const float* emb    = (const float*)d_in[1];
  const float* W0     = (const float*)d_in[2];
  const float* U0     = (const float*)d_in[3];
  const float* b0     = (const float*)d_in[4];
  const float* W1     = (const float*)d_in[5];
  const float* U1     = (const float*)d_in[6];
  const float* b1     = (const float*)d_in[7];
  const float* Wo     = (const float*)d_in[8];
  const float* bo     = (const float*)d_in[9];
  float* out = (float*)d_out;
  short* ws  = (short*)d_ws;

  const size_t W0P_SZ = (size_t)128 * 4 * 512;     // 262144
  const size_t UP_SZ  = (size_t)128 * 64 * 512;    // 4194304
  const size_t EP_SZ  = (size_t)SEQ * 16384;       // 1310720
  const size_t H_SZ   = (size_t)8 * 64 * 64 * 8;   // 262144 per buffer

  short* W0p = ws;
  short* U0p = W0p + W0P_SZ;
  short* W1p = U0p + UP_SZ;
  short* U1p = W1p + UP_SZ;
  short* Ep  = U1p + UP_SZ;
  short* hbase = Ep + EP_SZ;

  {
    int unitsW0 = (UNITS / 16) * (EPAD / 32);   // 512
    pack_b_kernel<<<(unitsW0 + 3) / 4, 256, 0, stream>>>(W0, EMB, UNITS, EPAD / 32, unitsW0, W0p);
    int unitsU = (UNITS / 16) * (UNITS / 32);   // 8192
    pack_b_kernel<<<(unitsU + 3) / 4, 256, 0, stream>>>(U0, UNITS, UNITS, UNITS / 32, unitsU, U0p);
    pack_b_kernel<<<(unitsU + 3) / 4, 256, 0, stream>>>(W1, UNITS, UNITS, UNITS / 32, unitsU, W1p);
    pack_b_kernel<<<(unitsU + 3) / 4, 256, 0, stream>>>(U1, UNITS, UNITS, UNITS / 32, unitsU, U1p);
    int ne = SEQ * 8 * 4 * 64;
    pack_e_kernel<<<(ne + 255) / 256, 256, 0, stream>>>(tokens, emb, Ep);
  }

  // zero all 8 h double-buffers (provides h_l[-1] = 0)
  hipMemsetAsync(hbase, 0, 8u * H_SZ * 2u, stream);

  // ---- 83 diagonals: s = t + l ----
  for (int s = 0; s <= SEQ - 1 + 3; ++s) {
    diag_kernel<<<256, 256, 0, stream>>>(Ep, W0p, U0p, W1p, U1p, b0, b1, hbase, s);
  }

  // final head: h3[SEQ-1] written at diagonal 82 (parity 0)
  head_kernel<<<BATCH, 256, 0, stream>>>(hbase + 6 * H_SZ, Wo, bo, out);
}